// Round 6
// baseline (68.775 us; speedup 1.0000x reference)
//
#include <hip/hip_runtime.h>
#include <hip/hip_bf16.h>

#define BB 8
#define NN 512
#define DD 256
#define NROWS (BB*NN)   // 4096
#define JT 16           // attn j-tile

using bf16x8 = __attribute__((ext_vector_type(8))) short;
using f32x4  = __attribute__((ext_vector_type(4))) float;
typedef unsigned short us_t;

__device__ __forceinline__ us_t f2bf(float x) {
    union { float f; unsigned int u; } v; v.f = x;
    unsigned int r = (v.u + 0x7fffu + ((v.u >> 16) & 1u)) >> 16;
    return (us_t)r;
}

// Weights f32 -> bf16 [d][k]
__global__ __launch_bounds__(256) void prep_w(
    const float* __restrict__ w1f, const float* __restrict__ w2f,
    us_t* __restrict__ o1, us_t* __restrict__ o2)
{
    int i = blockIdx.x*256 + threadIdx.x;
    o1[i] = f2bf(w1f[i]);
    o2[i] = f2bf(w2f[i]);
}

// MFMA linear + fused a/c scalars. 512 threads = 8 waves, wave w -> d slice of 32.
// Block: 16 rows x 256 d. Writes hT[b][d][i] bf16, a[row], c[row].
__global__ __launch_bounds__(512) void lin_mfma(
    const us_t* __restrict__ Wbf, const float* __restrict__ bias,
    const float* __restrict__ Xf, const us_t* __restrict__ Xb,
    const int* __restrict__ idx,
    const float* __restrict__ wvec, const int* __restrict__ flagidx,
    const float* __restrict__ flag_emb,
    us_t* __restrict__ hT, float* __restrict__ aout, float* __restrict__ cout)
{
    __shared__ float redA[128], redC[128];
    const int t = threadIdx.x;
    const int wave = t >> 6, lane = t & 63;
    const int lrow = lane & 15, kg = lane >> 4;
    const int r0 = blockIdx.x * 16;
    const int dw = wave * 32;

    const int arow = r0 + lrow;
    const int nid = idx ? idx[arow] : arow;

    f32x4 acc[2];
    #pragma unroll
    for (int n = 0; n < 2; ++n) acc[n] = (f32x4){0.f, 0.f, 0.f, 0.f};

    if (Xb) {
        const us_t* xr = Xb + (size_t)nid * DD;
        #pragma unroll
        for (int ks = 0; ks < DD/32; ++ks) {
            bf16x8 af = *(const bf16x8*)(xr + ks*32 + kg*8);
            #pragma unroll
            for (int n = 0; n < 2; ++n) {
                bf16x8 bf = *(const bf16x8*)(Wbf + (size_t)(dw + n*16 + lrow)*DD
                                              + ks*32 + kg*8);
                acc[n] = __builtin_amdgcn_mfma_f32_16x16x32_bf16(af, bf, acc[n], 0, 0, 0);
            }
        }
    } else {
        const float4* xr = (const float4*)(Xf + (size_t)nid * DD);
        #pragma unroll
        for (int ks = 0; ks < DD/32; ++ks) {
            float4 xa = xr[ks*8 + kg*2];
            float4 xb = xr[ks*8 + kg*2 + 1];
            bf16x8 af;
            af[0] = (short)f2bf(xa.x); af[1] = (short)f2bf(xa.y);
            af[2] = (short)f2bf(xa.z); af[3] = (short)f2bf(xa.w);
            af[4] = (short)f2bf(xb.x); af[5] = (short)f2bf(xb.y);
            af[6] = (short)f2bf(xb.z); af[7] = (short)f2bf(xb.w);
            #pragma unroll
            for (int n = 0; n < 2; ++n) {
                bf16x8 bf = *(const bf16x8*)(Wbf + (size_t)(dw + n*16 + lrow)*DD
                                              + ks*32 + kg*8);
                acc[n] = __builtin_amdgcn_mfma_f32_16x16x32_bf16(af, bf, acc[n], 0, 0, 0);
            }
        }
    }

    // epilogue: D row (m) = kg*4+r, D col (d) = dw + n*16 + lrow
    const int b  = r0 >> 9;
    const int i0 = (r0 & 511) + kg*4;
    float pa[4] = {0.f,0.f,0.f,0.f}, pc[4] = {0.f,0.f,0.f,0.f};
    #pragma unroll
    for (int n = 0; n < 2; ++n) {
        int d = dw + n*16 + lrow;
        float bv = bias[d];
        float whd = wvec[d], wtd = wvec[256+d];
        ushort4 u;
        #pragma unroll
        for (int r = 0; r < 4; ++r) {
            float v = acc[n][r] + bv;
            ((us_t*)&u)[r] = f2bf(v);
            pa[r] += v * whd;
            pc[r] += v * wtd;
        }
        *(ushort4*)&hT[(size_t)b*DD*NN + (size_t)d*NN + i0] = u;
    }
    #pragma unroll
    for (int r = 0; r < 4; ++r) {
        #pragma unroll
        for (int m = 1; m < 16; m <<= 1) {
            pa[r] += __shfl_xor(pa[r], m);
            pc[r] += __shfl_xor(pc[r], m);
        }
    }
    if (lrow == 0) {
        #pragma unroll
        for (int r = 0; r < 4; ++r) {
            redA[wave*16 + kg*4 + r] = pa[r];
            redC[wave*16 + kg*4 + r] = pc[r];
        }
    }
    __syncthreads();
    if (t < 128) {
        const int m = t >> 3, sub = t & 7;
        const int fi = flagidx[r0 + m];
        float fa = 0.f, fc = 0.f;
        #pragma unroll
        for (int q = 0; q < 4; ++q) {
            int e = sub*4 + q;
            float fe = flag_emb[fi*32 + e];
            fa += fe * wvec[512 + e];
            fc += fe * wvec[544 + e];
        }
        #pragma unroll
        for (int mm = 1; mm < 8; mm <<= 1) {
            fa += __shfl_xor(fa, mm);
            fc += __shfl_xor(fc, mm);
        }
        if (sub == 0) {
            float sa = fa, sc = fc;
            #pragma unroll
            for (int wv = 0; wv < 8; ++wv) { sa += redA[wv*16 + m]; sc += redC[wv*16 + m]; }
            aout[r0 + m] = sa;
            cout[r0 + m] = sc;
        }
    }
}

// One block per (b, 16-col tile), 512 threads (8 waves).
// Layer 1 (adj != null): reads raw adj/etype, writes packed bytes to pkout.
// Layer 2 (adj == null): reads packed bytes from pkin.
__global__ __launch_bounds__(512) void attn_fused(
    const int* __restrict__ adj, const int* __restrict__ etype,
    unsigned char* __restrict__ pkout, const unsigned char* __restrict__ pkin,
    const float* __restrict__ edge_emb, const float* __restrict__ w,
    const float* __restrict__ bptr,
    const float* __restrict__ a, const float* __restrict__ c,
    const us_t* __restrict__ hT,
    float* __restrict__ outf, us_t* __restrict__ outb)
{
    __shared__ __align__(16) float p[NN][JT+1];           // 34.8 KB
    __shared__ __align__(16) us_t Pb[JT][NN+8];           // 16.6 KB
    __shared__ float as[NN];
    __shared__ float edot[16];
    __shared__ float cjs[JT];
    __shared__ float red[32][JT];
    __shared__ float mj[JT];
    __shared__ float invden[JT];

    const int t = threadIdx.x;
    const int b  = blockIdx.x >> 5;
    const int j0 = (blockIdx.x & 31) * JT;

    as[t] = a[b*NN + t];
    if (t < 16) {
        float s = 0.f;
        for (int e2 = 0; e2 < 32; ++e2)
            s += edge_emb[t*32 + e2] * w[576 + e2];
        edot[t] = s;
    } else if (t < 32) {
        cjs[t-16] = c[b*NN + j0 + (t-16)];
    }
    const float bias = bptr[0];
    __syncthreads();

    // ---- logits: one row per thread ----
    {
        const int i = t;
        const int g = (b*NN + i)*NN + j0;
        const float base = as[i] + bias;
        if (adj) {
            int4 a4[4], e4[4];
            #pragma unroll
            for (int q = 0; q < 4; ++q) {
                a4[q] = *(const int4*)(adj + g + q*4);
                e4[q] = *(const int4*)(etype + g + q*4);
            }
            const int* av = (const int*)a4;
            const int* ev = (const int*)e4;
            unsigned int pw[4];
            #pragma unroll
            for (int q = 0; q < 4; ++q) {
                unsigned int acc_b = 0;
                #pragma unroll
                for (int s = 0; s < 4; ++s) {
                    int j = q*4 + s;
                    int ad = av[j], et = ev[j];
                    float l = base + cjs[j] + edot[et];
                    l = (l > 0.f) ? l : 0.1f*l;
                    p[i][j] = ad ? l : -1.0e30f;
                    acc_b |= (unsigned int)((et & 15) | (ad << 4)) << (s*8);
                }
                pw[q] = acc_b;
            }
            *(uint4*)(pkout + g) = *(const uint4*)pw;
        } else {
            uint4 u = *(const uint4*)(pkin + g);
            unsigned int pw[4] = {u.x, u.y, u.z, u.w};
            #pragma unroll
            for (int q = 0; q < 4; ++q) {
                #pragma unroll
                for (int s = 0; s < 4; ++s) {
                    int j = q*4 + s;
                    unsigned int byte = (pw[q] >> (s*8)) & 0xffu;
                    float l = base + cjs[j] + edot[byte & 15];
                    l = (l > 0.f) ? l : 0.1f*l;
                    p[i][j] = (byte >> 4) ? l : -1.0e30f;
                }
            }
        }
    }
    __syncthreads();

    // ---- softmax over i (per column j); grp 0..31 handles 16 i's ----
    const int j = t & 15, grp = t >> 4;
    float m = -3.0e38f;
    #pragma unroll
    for (int s = 0; s < 16; ++s) m = fmaxf(m, p[grp + s*32][j]);
    red[grp][j] = m;
    __syncthreads();
    if (t < 16) {
        float mm = red[0][t];
        for (int g2 = 1; g2 < 32; ++g2) mm = fmaxf(mm, red[g2][t]);
        mj[t] = mm;
    }
    __syncthreads();
    const float mmax = mj[j];
    float ssum = 0.f;
    #pragma unroll
    for (int s = 0; s < 16; ++s) {
        float v = __expf(p[grp + s*32][j] - mmax);
        p[grp + s*32][j] = v;
        ssum += v;
    }
    red[grp][j] = ssum;
    __syncthreads();
    if (t < 16) {
        float sm = 0.f;
        for (int g2 = 0; g2 < 32; ++g2) sm += red[g2][t];
        invden[t] = 1.f / sm;
    }
    __syncthreads();

    // ---- normalize + pack transposed bf16: Pb[j][i] ----
    const float inv = invden[j];
    #pragma unroll
    for (int s = 0; s < 8; ++s) {
        int i = grp*2 + s*64;
        ushort2 u;
        u.x = f2bf(p[i  ][j] * inv);
        u.y = f2bf(p[i+1][j] * inv);
        *(ushort2*)&Pb[j][i] = u;
    }
    __syncthreads();

    // ---- MFMA: out[16 j][256 d], wave w -> d slice of 32 ----
    const int wave = t >> 6, lane = t & 63;
    const int dw = wave * 32;
    const int lrow = lane & 15;          // A row (j) / B col (d)
    const int kg   = lane >> 4;          // k-group
    f32x4 acc[2];
    acc[0] = (f32x4){0.f,0.f,0.f,0.f};
    acc[1] = (f32x4){0.f,0.f,0.f,0.f};

    const us_t* hTb = hT + (size_t)b*DD*NN;
    const us_t* hp[2];
    hp[0] = hTb + (size_t)(dw + lrow)*NN + kg*8;
    hp[1] = hTb + (size_t)(dw + 16 + lrow)*NN + kg*8;

    #pragma unroll 4
    for (int ks = 0; ks < NN/32; ++ks) {
        int k0 = ks*32;
        bf16x8 afr = *(const bf16x8*)&Pb[lrow][kg*8 + k0];
        #pragma unroll
        for (int n = 0; n < 2; ++n) {
            bf16x8 bfr = *(const bf16x8*)(hp[n] + k0);
            acc[n] = __builtin_amdgcn_mfma_f32_16x16x32_bf16(afr, bfr, acc[n], 0, 0, 0);
        }
    }

    // ---- epilogue: C/D col=lane&15 (d), row=(lane>>4)*4+reg (j) ----
    #pragma unroll
    for (int n = 0; n < 2; ++n) {
        #pragma unroll
        for (int r = 0; r < 4; ++r) {
            float v = acc[n][r];
            int jj = j0 + kg*4 + r;
            int dd = dw + n*16 + lrow;
            size_t o = (size_t)(b*NN + jj)*DD + dd;
            if (outb) outb[o] = f2bf(1.f/(1.f + __expf(-v)));
            else      outf[o] = v;
        }
    }
}

extern "C" void kernel_launch(void* const* d_in, const int* in_sizes, int n_in,
                              void* d_out, int out_size, void* d_ws, size_t ws_size,
                              hipStream_t stream) {
    (void)in_sizes; (void)n_in; (void)out_size; (void)ws_size;
    const int*   adj       = (const int*)d_in[0];
    const int*   head_nodes= (const int*)d_in[1];
    const int*   head_flag = (const int*)d_in[2];
    const int*   etype     = (const int*)d_in[3];
    const float* node_emb  = (const float*)d_in[4];
    const float* edge_emb  = (const float*)d_in[5];
    const float* flag_emb  = (const float*)d_in[6];
    const float* t1_w      = (const float*)d_in[7];
    const float* t1_b      = (const float*)d_in[8];
    const float* w1        = (const float*)d_in[9];
    const float* b1        = (const float*)d_in[10];
    const float* t2_w      = (const float*)d_in[11];
    const float* t2_b      = (const float*)d_in[12];
    const float* w2        = (const float*)d_in[13];
    const float* b2        = (const float*)d_in[14];

    us_t* hT  = (us_t*)d_ws;                         // 2 MB bf16 [b][d][i]
    us_t* tt  = hT  + (size_t)NROWS*DD;              // 2 MB bf16 sigmoid(out1)
    us_t* Wb1 = tt  + (size_t)NROWS*DD;              // 128 KB
    us_t* Wb2 = Wb1 + (size_t)DD*DD;                 // 128 KB
    unsigned char* pk = (unsigned char*)(Wb2 + (size_t)DD*DD);  // 2 MB
    float* a1 = (float*)(pk + (size_t)BB*NN*NN);
    float* c1 = a1 + NROWS;
    float* a2 = c1 + NROWS;
    float* c2 = a2 + NROWS;

    prep_w<<<DD*DD/256, 256, 0, stream>>>(t1_w, t2_w, Wb1, Wb2);
    lin_mfma<<<NROWS/16, 512, 0, stream>>>(Wb1, t1_b, node_emb, nullptr, head_nodes,
                                           w1, head_flag, flag_emb, hT, a1, c1);
    attn_fused<<<BB*(NN/JT), 512, 0, stream>>>(adj, etype, pk, nullptr,
                                               edge_emb, w1, b1, a1, c1, hT,
                                               nullptr, tt);
    lin_mfma<<<NROWS/16, 512, 0, stream>>>(Wb2, t2_b, nullptr, tt, nullptr,
                                           w2, head_flag, flag_emb, hT, a2, c2);
    attn_fused<<<BB*(NN/16), 512, 0, stream>>>(nullptr, nullptr, nullptr, pk,
                                               edge_emb, w2, b2, a2, c2, hT,
                                               (float*)d_out, nullptr);
}